// Round 2
// baseline (1486.039 us; speedup 1.0000x reference)
//
#include <hip/hip_runtime.h>
#include <hip/hip_bf16.h>

#define IN_F 128
#define HID 16
#define OUT_F 64
#define XT_LD 132  // padded LDS stride for x tile (breaks bank conflicts)

// ---------- dtype-flex helpers (device-side runtime dtype detection) ----------
__device__ __forceinline__ float loadF(const void* p, size_t i, int bf) {
  if (bf) {
    unsigned v = ((unsigned)((const unsigned short*)p)[i]) << 16;
    float f; __builtin_memcpy(&f, &v, 4); return f;
  }
  return ((const float*)p)[i];
}
__device__ __forceinline__ int loadE(const void* p, size_t i, int i64) {
  if (i64) return (int)((const long long*)p)[i];
  return ((const int*)p)[i];
}
// nontemporal variant for the big edge-index streams (don't pollute L2)
__device__ __forceinline__ int loadE_nt(const void* p, size_t i, int i64) {
  if (i64) return (int)__builtin_nontemporal_load((const long long*)p + i);
  return __builtin_nontemporal_load((const int*)p + i);
}

// flags[0] = 1 if float tensors are bf16; flags[1] = 1 if edge_index is int64
__global__ void k_detect(const void* x, const void* ei, int* flags) {
  __shared__ int c_ok, c_hi;
  int t = threadIdx.x;
  if (t == 0) { c_ok = 0; c_hi = 0; }
  __syncthreads();
  const float* xf = (const float*)x;
  int ok = 0;
  for (int i = t; i < 1024; i += 256) {
    float v = fabsf(xf[i]);
    if (v > 1e-4f && v < 1e4f) ok++;   // N(0,1) f32 passes ~always; packed bf16 ~never
  }
  const int* ep = (const int*)ei;
  int hi = 0;
  for (int i = t; i < 1024; i += 256)
    if (ep[2*i + 1] != 0) hi++;        // int64 node ids < 2^31 -> high words all zero
  atomicAdd(&c_ok, ok);
  atomicAdd(&c_hi, hi);
  __syncthreads();
  if (t == 0) {
    flags[0] = (c_ok < 512) ? 1 : 0;
    flags[1] = (c_hi == 0) ? 1 : 0;
  }
}

// ---------- degree / normalization ----------
__global__ void k_init_deg(unsigned* deg, int n) {
  int i = blockIdx.x * 256 + threadIdx.x;
  if (i < n) deg[i] = 1u;  // self-loop
}
__global__ void k_count(const void* ei, const int* flags, unsigned* deg, int e) {
  int i = blockIdx.x * 256 + threadIdx.x;
  if (i >= e) return;
  int i64 = flags[1];
  int d = loadE_nt(ei, (size_t)e + i, i64);
  atomicAdd(&deg[d], 1u);
}
__global__ void k_dinv(const unsigned* deg, float* dinv, int n) {
  int i = blockIdx.x * 256 + threadIdx.x;
  if (i < n) dinv[i] = rsqrtf((float)deg[i]);
}

// ---------- hs1 = dinv[n] * (x @ W1) ----------
__global__ __launch_bounds__(256) void k_xw1(const void* x, const void* W1,
                                             const int* flags, const float* dinv,
                                             float* hs1, int n) {
  __shared__ float w[IN_F * HID];
  __shared__ float xt[16 * XT_LD];
  const int t = threadIdx.x;
  const int bf = flags[0];
  for (int i = t; i < IN_F * HID; i += 256) w[i] = loadF(W1, i, bf);
  const int n0 = blockIdx.x * 16;
  for (int i = t; i < 16 * IN_F; i += 256) {
    int rl = i >> 7, k = i & 127;
    int row = n0 + rl;
    xt[rl * XT_LD + k] = (row < n) ? loadF(x, (size_t)row * IN_F + k, bf) : 0.f;
  }
  __syncthreads();
  const int ln = t >> 4, c = t & 15;
  const int node = n0 + ln;
  if (node >= n) return;
  float acc = 0.f;
  #pragma unroll 16
  for (int k = 0; k < IN_F; ++k)
    acc = fmaf(xt[ln * XT_LD + k], w[k * HID + c], acc);
  hs1[(size_t)node * HID + c] = dinv[node] * acc;
}

// ---------- edge-parallel scatter-add: acc[dst] += tbl[src] (tbl pre-scaled) ----------
// thread i handles float4-quad (i&3) of edge (i>>2): 1 broadcast index load,
// 1 coalesced 16B gather, 4 HW fp32 atomics into the L2-resident accumulator.
__global__ __launch_bounds__(256) void k_edge(const void* ei, const int* flags,
                                              const float* tbl, float* acc, int e) {
  int i = blockIdx.x * 256 + threadIdx.x;
  int idx = i >> 2, q = i & 3;
  if (idx >= e) return;
  const int i64 = flags[1];
  int s = loadE_nt(ei, idx, i64);
  int d = loadE_nt(ei, (size_t)e + idx, i64);
  const float4 v = ((const float4*)(tbl + (size_t)s * HID))[q];
  float* a = acc + (size_t)d * HID + (q << 2);
  unsafeAtomicAdd(a + 0, v.x);
  unsafeAtomicAdd(a + 1, v.y);
  unsafeAtomicAdd(a + 2, v.z);
  unsafeAtomicAdd(a + 3, v.w);
}

// ---------- layer-1 epilogue: hd = dinv * relu(dinv*(acc + hs1_self) + b1); acc = 0 ----------
__global__ void k_post1(const float* dinv, float* acc, const float* hs1,
                        const void* b1, const int* flags, float* hd, int n) {
  int i = blockIdx.x * 256 + threadIdx.x;   // i over n*4 quads
  int node = i >> 2, q = i & 3;
  if (node >= n) return;
  const int bf = flags[0];
  const float di = dinv[node];
  float4 a = ((const float4*)(acc + (size_t)node * HID))[q];
  float4 sv = ((const float4*)(hs1 + (size_t)node * HID))[q];
  float4 o;
  o.x = di * fmaxf(fmaf(di, a.x + sv.x, loadF(b1, q * 4 + 0, bf)), 0.f);
  o.y = di * fmaxf(fmaf(di, a.y + sv.y, loadF(b1, q * 4 + 1, bf)), 0.f);
  o.z = di * fmaxf(fmaf(di, a.z + sv.z, loadF(b1, q * 4 + 2, bf)), 0.f);
  o.w = di * fmaxf(fmaf(di, a.w + sv.w, loadF(b1, q * 4 + 3, bf)), 0.f);
  ((float4*)(hd + (size_t)node * HID))[q] = o;
  ((float4*)(acc + (size_t)node * HID))[q] = make_float4(0.f, 0.f, 0.f, 0.f);  // ready for layer 2
}

// ---------- layer-2 epilogue: out = relu( (dinv*(acc + hd_self)) @ W2 + b2 ) ----------
__global__ __launch_bounds__(256) void k_post2(const float* dinv, const float* acc,
                                               const float* hd, const void* W2,
                                               const void* b2, const int* flags,
                                               void* out, int n) {
  __shared__ float w2s[HID * OUT_F];
  const int t = threadIdx.x;
  const int bf = flags[0];
  for (int i = t; i < HID * OUT_F; i += 256) w2s[i] = loadF(W2, i, bf);
  __syncthreads();
  const int gid = blockIdx.x * 256 + t;
  const int node = gid >> 6;
  if (node >= n) return;
  const int lane = t & 63;
  const float di = dinv[node];
  float zk = 0.f;
  if (lane < HID)
    zk = di * (acc[(size_t)node * HID + lane] + hd[(size_t)node * HID + lane]);
  float o = loadF(b2, lane, bf);
  #pragma unroll
  for (int k = 0; k < HID; ++k)
    o = fmaf(__shfl(zk, k, 64), w2s[k * OUT_F + lane], o);
  o = fmaxf(o, 0.f);
  size_t oi = (size_t)node * OUT_F + lane;
  if (bf) ((__hip_bfloat16*)out)[oi] = __float2bfloat16(o);
  else    ((float*)out)[oi] = o;
}

extern "C" void kernel_launch(void* const* d_in, const int* in_sizes, int n_in,
                              void* d_out, int out_size, void* d_ws, size_t ws_size,
                              hipStream_t stream) {
  const void* x  = d_in[0];
  const void* ei = d_in[1];
  const void* W1 = d_in[2];
  const void* b1 = d_in[3];
  const void* W2 = d_in[4];
  const void* b2 = d_in[5];
  const int n = in_sizes[0] / IN_F;
  const int e = in_sizes[1] / 2;

  char* p = (char*)d_ws;
  auto alloc = [&](size_t bytes) -> char* {
    char* r = p;
    p += (bytes + 255) & ~(size_t)255;
    return r;
  };
  int*      flags = (int*)alloc(256);
  unsigned* deg   = (unsigned*)alloc((size_t)n * 4);
  float*    dinv  = (float*)alloc((size_t)n * 4);
  float*    hs1   = (float*)alloc((size_t)n * HID * 4);
  float*    acc   = (float*)alloc((size_t)n * HID * 4);
  float*    hd    = (float*)alloc((size_t)n * HID * 4);

  const int nbN = (n + 255) / 256;
  const int nbE = (e + 255) / 256;
  const int nbQ = (4 * e + 255) / 256;   // edge kernels: 4 threads/edge
  const int nbP = (4 * n + 255) / 256;   // post1: 4 threads/node

  k_detect<<<1, 256, 0, stream>>>(x, ei, flags);
  hipMemsetAsync(acc, 0, (size_t)n * HID * 4, stream);
  k_init_deg<<<nbN, 256, 0, stream>>>(deg, n);
  k_count<<<nbE, 256, 0, stream>>>(ei, flags, deg, e);
  k_dinv<<<nbN, 256, 0, stream>>>(deg, dinv, n);
  k_xw1<<<(n + 15) / 16, 256, 0, stream>>>(x, W1, flags, dinv, hs1, n);
  k_edge<<<nbQ, 256, 0, stream>>>(ei, flags, hs1, acc, e);
  k_post1<<<nbP, 256, 0, stream>>>(dinv, acc, hs1, b1, flags, hd, n);
  k_edge<<<nbQ, 256, 0, stream>>>(ei, flags, hd, acc, e);
  k_post2<<<(n * 64 + 255) / 256, 256, 0, stream>>>(dinv, acc, hd, W2, b2, flags, d_out, n);
}

// Round 3
// 889.043 us; speedup vs baseline: 1.6715x; 1.6715x over previous
//
#include <hip/hip_runtime.h>
#include <hip/hip_bf16.h>

#define IN_F 128
#define HID 16
#define OUT_F 64
#define XT_LD 132   // padded LDS stride for x tile in k_xw1
#define BINW 128    // nodes per bin (dst >> 7)
#define MAXNB 1024  // supports n <= 131072
#define EPT 16      // edges per thread in bincount/scatter
#define ACC_LD 17   // padded accumulator stride (bank-spread for LDS atomics)

// ---------- dtype-flex helpers (device-side runtime dtype detection) ----------
__device__ __forceinline__ float loadF(const void* p, size_t i, int bf) {
  if (bf) {
    unsigned v = ((unsigned)((const unsigned short*)p)[i]) << 16;
    float f; __builtin_memcpy(&f, &v, 4); return f;
  }
  return ((const float*)p)[i];
}
__device__ __forceinline__ int loadE_nt(const void* p, size_t i, int i64) {
  if (i64) return __builtin_nontemporal_load((const int*)p + 2 * i);  // little-endian low word
  return __builtin_nontemporal_load((const int*)p + i);
}

// flags[0] = 1 if float tensors are bf16; flags[1] = 1 if edge_index is int64
__global__ void k_detect(const void* x, const void* ei, int* flags) {
  __shared__ int c_ok, c_hi;
  int t = threadIdx.x;
  if (t == 0) { c_ok = 0; c_hi = 0; }
  __syncthreads();
  const float* xf = (const float*)x;
  int ok = 0;
  for (int i = t; i < 1024; i += 256) {
    float v = fabsf(xf[i]);
    if (v > 1e-4f && v < 1e4f) ok++;   // N(0,1) f32 passes ~always; packed bf16 ~never
  }
  const int* ep = (const int*)ei;
  int hi = 0;
  for (int i = t; i < 1024; i += 256)
    if (ep[2 * i + 1] != 0) hi++;      // int64 ids < 2^31 -> high words all zero
  atomicAdd(&c_ok, ok);
  atomicAdd(&c_hi, hi);
  __syncthreads();
  if (t == 0) {
    flags[0] = (c_ok < 512) ? 1 : 0;
    flags[1] = (c_hi == 0) ? 1 : 0;
  }
}

// ---------- pass 1: per-bin edge counts (LDS histogram, few global atomics) ----------
__global__ __launch_bounds__(256) void k_bincount(const void* ei, const int* flags,
                                                  unsigned* gcnt, int e, int nb) {
  __shared__ unsigned hist[MAXNB];
  const int t = threadIdx.x;
  for (int i = t; i < nb; i += 256) hist[i] = 0;
  __syncthreads();
  const int i64 = flags[1];
  const size_t base = (size_t)blockIdx.x * (256 * EPT);
  #pragma unroll
  for (int j = 0; j < EPT; ++j) {
    size_t idx = base + (size_t)j * 256 + t;
    if (idx < (size_t)e) {
      int d = loadE_nt(ei, (size_t)e + idx, i64);
      atomicAdd(&hist[d >> 7], 1u);
    }
  }
  __syncthreads();
  for (int i = t; i < nb; i += 256)
    if (hist[i]) atomicAdd(&gcnt[i], hist[i]);
}

// ---------- exclusive scan over nb (<=1024) bin counts; also primes gcur ----------
__global__ __launch_bounds__(256) void k_scan(const unsigned* gcnt, unsigned* offs,
                                              unsigned* gcur, int nb) {
  __shared__ unsigned s[256];
  const int t = threadIdx.x;
  unsigned c[4]; unsigned sum = 0;
  #pragma unroll
  for (int j = 0; j < 4; ++j) {
    int i = t * 4 + j;
    c[j] = (i < nb) ? gcnt[i] : 0u;
    sum += c[j];
  }
  s[t] = sum; __syncthreads();
  for (int d = 1; d < 256; d <<= 1) {
    unsigned a = (t >= d) ? s[t - d] : 0u;
    __syncthreads();
    s[t] += a;
    __syncthreads();
  }
  unsigned run = s[t] - sum;   // exclusive prefix of this thread's chunk
  #pragma unroll
  for (int j = 0; j < 4; ++j) {
    int i = t * 4 + j;
    if (i < nb) { offs[i] = run; gcur[i] = run; run += c[j]; }
  }
}

// ---------- pass 2: scatter edges into bins (wg-bulk reservation -> streaming writes) ----------
__global__ __launch_bounds__(256) void k_scatter(const void* ei, const int* flags,
                                                 unsigned* gcur, unsigned* binbuf,
                                                 int e, int nb) {
  __shared__ unsigned hist[MAXNB];
  __shared__ unsigned rbase[MAXNB];
  const int t = threadIdx.x;
  for (int i = t; i < nb; i += 256) hist[i] = 0;
  __syncthreads();
  const int i64 = flags[1];
  const size_t base = (size_t)blockIdx.x * (256 * EPT);
  unsigned pk[EPT]; int bn[EPT];
  #pragma unroll
  for (int j = 0; j < EPT; ++j) {
    size_t idx = base + (size_t)j * 256 + t;
    if (idx < (size_t)e) {
      int s = loadE_nt(ei, idx, i64);
      int d = loadE_nt(ei, (size_t)e + idx, i64);
      bn[j] = d >> 7;
      pk[j] = (unsigned)s | ((unsigned)(d & 127) << 17);
      atomicAdd(&hist[bn[j]], 1u);
    } else bn[j] = -1;
  }
  __syncthreads();
  for (int i = t; i < nb; i += 256) {
    unsigned h = hist[i];
    rbase[i] = h ? atomicAdd(&gcur[i], h) : 0u;
    hist[i] = 0;                       // reuse as per-wg cursor
  }
  __syncthreads();
  #pragma unroll
  for (int j = 0; j < EPT; ++j)
    if (bn[j] >= 0) {
      unsigned p = rbase[bn[j]] + atomicAdd(&hist[bn[j]], 1u);
      __builtin_nontemporal_store(pk[j], binbuf + p);
    }
}

// ---------- per-bin degree -> dinv (no global atomics) ----------
__global__ __launch_bounds__(256) void k_deg(const unsigned* binbuf, const unsigned* offs,
                                             const unsigned* gcnt, float* dinv, int n) {
  __shared__ unsigned dcnt[BINW];
  const int b = blockIdx.x, t = threadIdx.x;
  if (t < BINW) dcnt[t] = 0;
  __syncthreads();
  const unsigned off = offs[b], cnt = gcnt[b];
  for (unsigned i = t; i < cnt; i += 256)
    atomicAdd(&dcnt[binbuf[off + i] >> 17], 1u);
  __syncthreads();
  if (t < BINW) {
    int g = b * BINW + t;
    if (g < n) dinv[g] = rsqrtf((float)(dcnt[t] + 1u));  // +1 self-loop
  }
}

// ---------- hs1 = dinv[n] * (x @ W1) ----------
__global__ __launch_bounds__(256) void k_xw1(const void* x, const void* W1,
                                             const int* flags, const float* dinv,
                                             float* hs1, int n) {
  __shared__ float w[IN_F * HID];
  __shared__ float xt[16 * XT_LD];
  const int t = threadIdx.x;
  const int bf = flags[0];
  for (int i = t; i < IN_F * HID; i += 256) w[i] = loadF(W1, i, bf);
  const int n0 = blockIdx.x * 16;
  for (int i = t; i < 16 * IN_F; i += 256) {
    int rl = i >> 7, k = i & 127;
    int row = n0 + rl;
    xt[rl * XT_LD + k] = (row < n) ? loadF(x, (size_t)row * IN_F + k, bf) : 0.f;
  }
  __syncthreads();
  const int ln = t >> 4, c = t & 15;
  const int node = n0 + ln;
  if (node >= n) return;
  float acc = 0.f;
  #pragma unroll 16
  for (int k = 0; k < IN_F; ++k)
    acc = fmaf(xt[ln * XT_LD + k], w[k * HID + c], acc);
  hs1[(size_t)node * HID + c] = dinv[node] * acc;
}

// ---------- layer-1 aggregation: per-bin LDS accumulate + fused epilogue ----------
__global__ __launch_bounds__(512) void k_agg1(const unsigned* binbuf, const unsigned* offs,
                                              const unsigned* gcnt, const float* dinv,
                                              const float* hs1, const void* b1,
                                              const int* flags, float* hd, int n) {
  __shared__ float acc[BINW * ACC_LD];
  const int b = blockIdx.x, t = threadIdx.x;
  for (int i = t; i < BINW * ACC_LD; i += 512) acc[i] = 0.f;
  __syncthreads();
  const unsigned off = offs[b], cnt = gcnt[b];
  for (unsigned i = t; i < cnt; i += 512) {
    unsigned pk = binbuf[off + i];
    unsigned src = pk & 0x1FFFFu, dl = pk >> 17;
    const float4* hp = (const float4*)(hs1 + (size_t)src * HID);
    float4 v0 = hp[0], v1 = hp[1], v2 = hp[2], v3 = hp[3];
    float* ap = acc + dl * ACC_LD;
    atomicAdd(ap + 0,  v0.x); atomicAdd(ap + 1,  v0.y);
    atomicAdd(ap + 2,  v0.z); atomicAdd(ap + 3,  v0.w);
    atomicAdd(ap + 4,  v1.x); atomicAdd(ap + 5,  v1.y);
    atomicAdd(ap + 6,  v1.z); atomicAdd(ap + 7,  v1.w);
    atomicAdd(ap + 8,  v2.x); atomicAdd(ap + 9,  v2.y);
    atomicAdd(ap + 10, v2.z); atomicAdd(ap + 11, v2.w);
    atomicAdd(ap + 12, v3.x); atomicAdd(ap + 13, v3.y);
    atomicAdd(ap + 14, v3.z); atomicAdd(ap + 15, v3.w);
  }
  __syncthreads();
  const int bf = flags[0];
  for (int i = t; i < BINW * HID; i += 512) {
    int nl = i >> 4, ch = i & 15;
    int g = b * BINW + nl;
    if (g < n) {
      float di = dinv[g];
      float v = acc[nl * ACC_LD + ch] + hs1[(size_t)g * HID + ch];  // + self-loop
      hd[(size_t)g * HID + ch] = di * fmaxf(fmaf(di, v, loadF(b1, ch, bf)), 0.f);
    }
  }
}

// ---------- layer-2 aggregation + fused 16->64 transform + relu ----------
__global__ __launch_bounds__(512) void k_agg2(const unsigned* binbuf, const unsigned* offs,
                                              const unsigned* gcnt, const float* dinv,
                                              const float* hd, const void* W2,
                                              const void* b2, const int* flags,
                                              void* out, int n) {
  __shared__ float acc[BINW * ACC_LD];
  __shared__ float w2s[HID * OUT_F];
  const int b = blockIdx.x, t = threadIdx.x;
  const int bf = flags[0];
  for (int i = t; i < HID * OUT_F; i += 512) w2s[i] = loadF(W2, i, bf);
  for (int i = t; i < BINW * ACC_LD; i += 512) acc[i] = 0.f;
  __syncthreads();
  const unsigned off = offs[b], cnt = gcnt[b];
  for (unsigned i = t; i < cnt; i += 512) {
    unsigned pk = binbuf[off + i];
    unsigned src = pk & 0x1FFFFu, dl = pk >> 17;
    const float4* hp = (const float4*)(hd + (size_t)src * HID);
    float4 v0 = hp[0], v1 = hp[1], v2 = hp[2], v3 = hp[3];
    float* ap = acc + dl * ACC_LD;
    atomicAdd(ap + 0,  v0.x); atomicAdd(ap + 1,  v0.y);
    atomicAdd(ap + 2,  v0.z); atomicAdd(ap + 3,  v0.w);
    atomicAdd(ap + 4,  v1.x); atomicAdd(ap + 5,  v1.y);
    atomicAdd(ap + 6,  v1.z); atomicAdd(ap + 7,  v1.w);
    atomicAdd(ap + 8,  v2.x); atomicAdd(ap + 9,  v2.y);
    atomicAdd(ap + 10, v2.z); atomicAdd(ap + 11, v2.w);
    atomicAdd(ap + 12, v3.x); atomicAdd(ap + 13, v3.y);
    atomicAdd(ap + 14, v3.z); atomicAdd(ap + 15, v3.w);
  }
  __syncthreads();
  // z = dinv * (acc + self) back into LDS
  for (int i = t; i < BINW * HID; i += 512) {
    int nl = i >> 4, ch = i & 15;
    int g = b * BINW + nl;
    if (g < n) {
      float di = dinv[g];
      acc[nl * ACC_LD + ch] = di * (acc[nl * ACC_LD + ch] + hd[(size_t)g * HID + ch]);
    }
  }
  __syncthreads();
  // out[g][o] = relu(z[g] . W2[:,o] + b2[o])
  for (int i = t; i < BINW * OUT_F; i += 512) {
    int nl = i >> 6, o = i & 63;
    int g = b * BINW + nl;
    if (g >= n) continue;
    float val = loadF(b2, o, bf);
    #pragma unroll
    for (int ch = 0; ch < HID; ++ch)
      val = fmaf(acc[nl * ACC_LD + ch], w2s[ch * OUT_F + o], val);
    val = fmaxf(val, 0.f);
    size_t oi = (size_t)g * OUT_F + o;
    if (bf) ((__hip_bfloat16*)out)[oi] = __float2bfloat16(val);
    else    ((float*)out)[oi] = val;
  }
}

extern "C" void kernel_launch(void* const* d_in, const int* in_sizes, int n_in,
                              void* d_out, int out_size, void* d_ws, size_t ws_size,
                              hipStream_t stream) {
  const void* x  = d_in[0];
  const void* ei = d_in[1];
  const void* W1 = d_in[2];
  const void* b1 = d_in[3];
  const void* W2 = d_in[4];
  const void* b2 = d_in[5];
  const int n = in_sizes[0] / IN_F;
  const int e = in_sizes[1] / 2;
  const int nb = (n + BINW - 1) / BINW;

  char* p = (char*)d_ws;
  auto alloc = [&](size_t bytes) -> char* {
    char* r = p;
    p += (bytes + 255) & ~(size_t)255;
    return r;
  };
  int*      flags  = (int*)alloc(256);
  unsigned* gcnt   = (unsigned*)alloc(MAXNB * 4);
  unsigned* offs   = (unsigned*)alloc(MAXNB * 4);
  unsigned* gcur   = (unsigned*)alloc(MAXNB * 4);
  float*    dinv   = (float*)alloc((size_t)n * 4);
  float*    hs1    = (float*)alloc((size_t)n * HID * 4);
  float*    hd     = (float*)alloc((size_t)n * HID * 4);
  unsigned* binbuf = (unsigned*)alloc((size_t)e * 4);

  const int nbE = (e + 256 * EPT - 1) / (256 * EPT);

  k_detect<<<1, 256, 0, stream>>>(x, ei, flags);
  hipMemsetAsync(gcnt, 0, MAXNB * 4, stream);
  k_bincount<<<nbE, 256, 0, stream>>>(ei, flags, gcnt, e, nb);
  k_scan<<<1, 256, 0, stream>>>(gcnt, offs, gcur, nb);
  k_scatter<<<nbE, 256, 0, stream>>>(ei, flags, gcur, binbuf, e, nb);
  k_deg<<<nb, 256, 0, stream>>>(binbuf, offs, gcnt, dinv, n);
  k_xw1<<<(n + 15) / 16, 256, 0, stream>>>(x, W1, flags, dinv, hs1, n);
  k_agg1<<<nb, 512, 0, stream>>>(binbuf, offs, gcnt, dinv, hs1, b1, flags, hd, n);
  k_agg2<<<nb, 512, 0, stream>>>(binbuf, offs, gcnt, dinv, hd, W2, b2, flags, d_out, n);
}

// Round 4
// 351.147 us; speedup vs baseline: 4.2320x; 2.5318x over previous
//
#include <hip/hip_runtime.h>
#include <hip/hip_bf16.h>

#define IN_F 128
#define HID 16
#define OUT_F 64
#define XT_LD 132   // padded LDS stride for x tile in k_xw1
#define BINW 128    // nodes per bin (dst >> 7)
#define MAXNB 1024  // supports n <= 131072
#define EPT 16      // edges per thread in bincount/scatter

// ---------- dtype-flex helpers (device-side runtime dtype detection) ----------
__device__ __forceinline__ float loadF(const void* p, size_t i, int bf) {
  if (bf) {
    unsigned v = ((unsigned)((const unsigned short*)p)[i]) << 16;
    float f; __builtin_memcpy(&f, &v, 4); return f;
  }
  return ((const float*)p)[i];
}
__device__ __forceinline__ int loadE_nt(const void* p, size_t i, int i64) {
  if (i64) return __builtin_nontemporal_load((const int*)p + 2 * i);  // little-endian low word
  return __builtin_nontemporal_load((const int*)p + i);
}

// flags[0] = 1 if float tensors are bf16; flags[1] = 1 if edge_index is int64
__global__ void k_detect(const void* x, const void* ei, int* flags) {
  __shared__ int c_ok, c_hi;
  int t = threadIdx.x;
  if (t == 0) { c_ok = 0; c_hi = 0; }
  __syncthreads();
  const float* xf = (const float*)x;
  int ok = 0;
  for (int i = t; i < 1024; i += 256) {
    float v = fabsf(xf[i]);
    if (v > 1e-4f && v < 1e4f) ok++;   // N(0,1) f32 passes ~always; packed bf16 ~never
  }
  const int* ep = (const int*)ei;
  int hi = 0;
  for (int i = t; i < 1024; i += 256)
    if (ep[2 * i + 1] != 0) hi++;      // int64 ids < 2^31 -> high words all zero
  atomicAdd(&c_ok, ok);
  atomicAdd(&c_hi, hi);
  __syncthreads();
  if (t == 0) {
    flags[0] = (c_ok < 512) ? 1 : 0;
    flags[1] = (c_hi == 0) ? 1 : 0;
  }
}

// ---------- pass 1: per-bin edge counts (LDS histogram, few global atomics) ----------
__global__ __launch_bounds__(256) void k_bincount(const void* ei, const int* flags,
                                                  unsigned* gcnt, int e, int nb) {
  __shared__ unsigned hist[MAXNB];
  const int t = threadIdx.x;
  for (int i = t; i < nb; i += 256) hist[i] = 0;
  __syncthreads();
  const int i64 = flags[1];
  const size_t base = (size_t)blockIdx.x * (256 * EPT);
  #pragma unroll
  for (int j = 0; j < EPT; ++j) {
    size_t idx = base + (size_t)j * 256 + t;
    if (idx < (size_t)e) {
      int d = loadE_nt(ei, (size_t)e + idx, i64);
      atomicAdd(&hist[d >> 7], 1u);
    }
  }
  __syncthreads();
  for (int i = t; i < nb; i += 256)
    if (hist[i]) atomicAdd(&gcnt[i], hist[i]);
}

// ---------- exclusive scan over nb (<=1024) bin counts; also primes gcur ----------
__global__ __launch_bounds__(256) void k_scan(const unsigned* gcnt, unsigned* offs,
                                              unsigned* gcur, int nb) {
  __shared__ unsigned s[256];
  const int t = threadIdx.x;
  unsigned c[4]; unsigned sum = 0;
  #pragma unroll
  for (int j = 0; j < 4; ++j) {
    int i = t * 4 + j;
    c[j] = (i < nb) ? gcnt[i] : 0u;
    sum += c[j];
  }
  s[t] = sum; __syncthreads();
  for (int d = 1; d < 256; d <<= 1) {
    unsigned a = (t >= d) ? s[t - d] : 0u;
    __syncthreads();
    s[t] += a;
    __syncthreads();
  }
  unsigned run = s[t] - sum;   // exclusive prefix of this thread's chunk
  #pragma unroll
  for (int j = 0; j < 4; ++j) {
    int i = t * 4 + j;
    if (i < nb) { offs[i] = run; gcur[i] = run; run += c[j]; }
  }
}

// ---------- pass 2: scatter edges into bins (wg-bulk reservation -> streaming writes) ----------
__global__ __launch_bounds__(256) void k_scatter(const void* ei, const int* flags,
                                                 unsigned* gcur, unsigned* binbuf,
                                                 int e, int nb) {
  __shared__ unsigned hist[MAXNB];
  __shared__ unsigned rbase[MAXNB];
  const int t = threadIdx.x;
  for (int i = t; i < nb; i += 256) hist[i] = 0;
  __syncthreads();
  const int i64 = flags[1];
  const size_t base = (size_t)blockIdx.x * (256 * EPT);
  unsigned pk[EPT]; int bn[EPT];
  #pragma unroll
  for (int j = 0; j < EPT; ++j) {
    size_t idx = base + (size_t)j * 256 + t;
    if (idx < (size_t)e) {
      int s = loadE_nt(ei, idx, i64);
      int d = loadE_nt(ei, (size_t)e + idx, i64);
      bn[j] = d >> 7;
      pk[j] = (unsigned)s | ((unsigned)(d & 127) << 17);
      atomicAdd(&hist[bn[j]], 1u);
    } else bn[j] = -1;
  }
  __syncthreads();
  for (int i = t; i < nb; i += 256) {
    unsigned h = hist[i];
    rbase[i] = h ? atomicAdd(&gcur[i], h) : 0u;
    hist[i] = 0;                       // reuse as per-wg cursor
  }
  __syncthreads();
  #pragma unroll
  for (int j = 0; j < EPT; ++j)
    if (bn[j] >= 0) {
      unsigned p = rbase[bn[j]] + atomicAdd(&hist[bn[j]], 1u);
      __builtin_nontemporal_store(pk[j], binbuf + p);
    }
}

// ---------- pass 3: within-bin counting sort by local dst -> per-node CSR ----------
// Also derives degree -> dinv and per-node row offsets (offs2). Writes land in a
// 16KB window per wg -> L2 write-combines -> streaming HBM traffic.
__global__ __launch_bounds__(256) void k_sort(const unsigned* binbuf, const unsigned* offs,
                                              const unsigned* gcnt, unsigned* csr,
                                              unsigned* offs2, float* dinv, int n, int e) {
  __shared__ unsigned hist[BINW];
  __shared__ unsigned scn[BINW];
  __shared__ unsigned cur[BINW];
  const int b = blockIdx.x, t = threadIdx.x;
  if (t < BINW) hist[t] = 0;
  __syncthreads();
  const unsigned off = offs[b], cnt = gcnt[b];
  for (unsigned i = t; i < cnt; i += 256)
    atomicAdd(&hist[binbuf[off + i] >> 17], 1u);
  __syncthreads();
  if (t < BINW) scn[t] = hist[t];
  __syncthreads();
  for (int d = 1; d < BINW; d <<= 1) {
    unsigned a = (t >= d && t < BINW) ? scn[t - d] : 0u;
    __syncthreads();
    if (t < BINW) scn[t] += a;
    __syncthreads();
  }
  if (t < BINW) {
    unsigned excl = scn[t] - hist[t];
    cur[t] = excl;
    int g = b * BINW + t;
    if (g < n) {
      offs2[g] = off + excl;
      dinv[g] = rsqrtf((float)(hist[t] + 1u));   // +1 self-loop
    }
  }
  if (b == 0 && t == 0) offs2[n] = (unsigned)e;  // sentinel
  __syncthreads();
  for (unsigned i = t; i < cnt; i += 256) {
    unsigned pk = binbuf[off + i];
    unsigned dl = pk >> 17;
    unsigned p = atomicAdd(&cur[dl], 1u);
    csr[off + p] = pk & 0x1FFFFu;
  }
}

// ---------- hs1 = dinv[n] * (x @ W1) ----------
__global__ __launch_bounds__(256) void k_xw1(const void* x, const void* W1,
                                             const int* flags, const float* dinv,
                                             float* hs1, int n) {
  __shared__ float w[IN_F * HID];
  __shared__ float xt[16 * XT_LD];
  const int t = threadIdx.x;
  const int bf = flags[0];
  for (int i = t; i < IN_F * HID; i += 256) w[i] = loadF(W1, i, bf);
  const int n0 = blockIdx.x * 16;
  for (int i = t; i < 16 * IN_F; i += 256) {
    int rl = i >> 7, k = i & 127;
    int row = n0 + rl;
    xt[rl * XT_LD + k] = (row < n) ? loadF(x, (size_t)row * IN_F + k, bf) : 0.f;
  }
  __syncthreads();
  const int ln = t >> 4, c = t & 15;
  const int node = n0 + ln;
  if (node >= n) return;
  float acc = 0.f;
  #pragma unroll 16
  for (int k = 0; k < IN_F; ++k)
    acc = fmaf(xt[ln * XT_LD + k], w[k * HID + c], acc);
  hs1[(size_t)node * HID + c] = dinv[node] * acc;
}

// ---------- layer-1 aggregation: wave-per-node gather + register accumulate ----------
__global__ __launch_bounds__(256) void k_agg1(const unsigned* csr, const unsigned* offs2,
                                              const float* dinv, const float* hs1,
                                              const void* b1, const int* flags,
                                              float* hd, int n) {
  const int wid = (blockIdx.x * 256 + threadIdx.x) >> 6;
  if (wid >= n) return;
  const int lane = threadIdx.x & 63;
  const int sub = lane >> 2, ch = lane & 3;
  const unsigned off = offs2[wid];
  const unsigned cnt = offs2[wid + 1] - off;
  float4 acc = make_float4(0.f, 0.f, 0.f, 0.f);
  for (unsigned i = sub; i < cnt; i += 16) {
    unsigned s = __builtin_nontemporal_load(csr + off + i);
    const float4 v = ((const float4*)(hs1 + (size_t)s * HID))[ch];
    acc.x += v.x; acc.y += v.y; acc.z += v.z; acc.w += v.w;
  }
  #pragma unroll
  for (int m = 4; m < 64; m <<= 1) {
    acc.x += __shfl_xor(acc.x, m, 64);
    acc.y += __shfl_xor(acc.y, m, 64);
    acc.z += __shfl_xor(acc.z, m, 64);
    acc.w += __shfl_xor(acc.w, m, 64);
  }
  if (lane < 4) {
    const float di = dinv[wid];
    const float4 sv = ((const float4*)(hs1 + (size_t)wid * HID))[ch];
    const int bf = flags[0];
    float4 o;
    o.x = di * fmaxf(fmaf(di, acc.x + sv.x, loadF(b1, ch * 4 + 0, bf)), 0.f);
    o.y = di * fmaxf(fmaf(di, acc.y + sv.y, loadF(b1, ch * 4 + 1, bf)), 0.f);
    o.z = di * fmaxf(fmaf(di, acc.z + sv.z, loadF(b1, ch * 4 + 2, bf)), 0.f);
    o.w = di * fmaxf(fmaf(di, acc.w + sv.w, loadF(b1, ch * 4 + 3, bf)), 0.f);
    ((float4*)(hd + (size_t)wid * HID))[ch] = o;
  }
}

// ---------- layer-2 aggregation + fused 16->64 transform + relu ----------
__global__ __launch_bounds__(256) void k_agg2(const unsigned* csr, const unsigned* offs2,
                                              const float* dinv, const float* hd,
                                              const void* W2, const void* b2,
                                              const int* flags, void* out, int n) {
  __shared__ float w2s[HID * OUT_F];
  const int t = threadIdx.x;
  const int bf = flags[0];
  for (int i = t; i < HID * OUT_F; i += 256) w2s[i] = loadF(W2, i, bf);
  __syncthreads();
  const int wid = (blockIdx.x * 256 + t) >> 6;
  if (wid >= n) return;
  const int lane = t & 63;
  const int sub = lane >> 2, ch = lane & 3;
  const unsigned off = offs2[wid];
  const unsigned cnt = offs2[wid + 1] - off;
  float4 acc = make_float4(0.f, 0.f, 0.f, 0.f);
  for (unsigned i = sub; i < cnt; i += 16) {
    unsigned s = __builtin_nontemporal_load(csr + off + i);
    const float4 v = ((const float4*)(hd + (size_t)s * HID))[ch];
    acc.x += v.x; acc.y += v.y; acc.z += v.z; acc.w += v.w;
  }
  #pragma unroll
  for (int m = 4; m < 64; m <<= 1) {
    acc.x += __shfl_xor(acc.x, m, 64);
    acc.y += __shfl_xor(acc.y, m, 64);
    acc.z += __shfl_xor(acc.z, m, 64);
    acc.w += __shfl_xor(acc.w, m, 64);
  }
  const float di = dinv[wid];
  const float4 sv = ((const float4*)(hd + (size_t)wid * HID))[ch];
  acc.x = di * (acc.x + sv.x);
  acc.y = di * (acc.y + sv.y);
  acc.z = di * (acc.z + sv.z);
  acc.w = di * (acc.w + sv.w);
  float a[16];
  #pragma unroll
  for (int j = 0; j < 4; ++j) {
    a[4 * j + 0] = __shfl(acc.x, j, 64);
    a[4 * j + 1] = __shfl(acc.y, j, 64);
    a[4 * j + 2] = __shfl(acc.z, j, 64);
    a[4 * j + 3] = __shfl(acc.w, j, 64);
  }
  float o = loadF(b2, lane, bf);
  #pragma unroll
  for (int k = 0; k < HID; ++k) o = fmaf(a[k], w2s[k * OUT_F + lane], o);
  o = fmaxf(o, 0.f);
  size_t oi = (size_t)wid * OUT_F + lane;
  if (bf) ((__hip_bfloat16*)out)[oi] = __float2bfloat16(o);
  else    ((float*)out)[oi] = o;
}

extern "C" void kernel_launch(void* const* d_in, const int* in_sizes, int n_in,
                              void* d_out, int out_size, void* d_ws, size_t ws_size,
                              hipStream_t stream) {
  const void* x  = d_in[0];
  const void* ei = d_in[1];
  const void* W1 = d_in[2];
  const void* b1 = d_in[3];
  const void* W2 = d_in[4];
  const void* b2 = d_in[5];
  const int n = in_sizes[0] / IN_F;
  const int e = in_sizes[1] / 2;
  const int nb = (n + BINW - 1) / BINW;

  char* p = (char*)d_ws;
  auto alloc = [&](size_t bytes) -> char* {
    char* r = p;
    p += (bytes + 255) & ~(size_t)255;
    return r;
  };
  int*      flags  = (int*)alloc(256);
  unsigned* gcnt   = (unsigned*)alloc(MAXNB * 4);
  unsigned* offs   = (unsigned*)alloc(MAXNB * 4);
  unsigned* gcur   = (unsigned*)alloc(MAXNB * 4);
  float*    dinv   = (float*)alloc((size_t)n * 4);
  unsigned* offs2  = (unsigned*)alloc(((size_t)n + 1) * 4);
  float*    hs1    = (float*)alloc((size_t)n * HID * 4);
  float*    hd     = (float*)alloc((size_t)n * HID * 4);
  unsigned* binbuf = (unsigned*)alloc((size_t)e * 4);
  unsigned* csr    = (unsigned*)alloc((size_t)e * 4);

  const int nbE = (e + 256 * EPT - 1) / (256 * EPT);

  k_detect<<<1, 256, 0, stream>>>(x, ei, flags);
  hipMemsetAsync(gcnt, 0, MAXNB * 4, stream);
  k_bincount<<<nbE, 256, 0, stream>>>(ei, flags, gcnt, e, nb);
  k_scan<<<1, 256, 0, stream>>>(gcnt, offs, gcur, nb);
  k_scatter<<<nbE, 256, 0, stream>>>(ei, flags, gcur, binbuf, e, nb);
  k_sort<<<nb, 256, 0, stream>>>(binbuf, offs, gcnt, csr, offs2, dinv, n, e);
  k_xw1<<<(n + 15) / 16, 256, 0, stream>>>(x, W1, flags, dinv, hs1, n);
  k_agg1<<<(n + 3) / 4, 256, 0, stream>>>(csr, offs2, dinv, hs1, b1, flags, hd, n);
  k_agg2<<<(n + 3) / 4, 256, 0, stream>>>(csr, offs2, dinv, hd, W2, b2, flags, d_out, n);
}